// Round 14
// baseline (678.037 us; speedup 1.0000x reference)
//
#include <hip/hip_runtime.h>
#include <hip/hip_bf16.h>
#include <stdint.h>

typedef __attribute__((ext_vector_type(8))) short short8;
typedef __attribute__((ext_vector_type(4))) float f32x4;
typedef unsigned short u16;

#define SCALE_F 0.17677669529663687f

__device__ __forceinline__ u16 f2bf(float f){
  union { float f; unsigned u; } x; x.f = f;
  unsigned r = x.u + 0x7fffu + ((x.u >> 16) & 1u);
  return (u16)(r >> 16);
}
__device__ __forceinline__ float bf2f(u16 u){
  union { float f; unsigned u; } x; x.u = ((unsigned)u) << 16; return x.f;
}
// XOR-swizzled LDS byte address within a row (rowb bytes/row)
__device__ __forceinline__ unsigned swz(unsigned base, int row, unsigned rowb, unsigned colb){
  return base + (unsigned)row * rowb + (colb ^ (((unsigned)row & 7u) << 4));
}
// async global->LDS 16B
__device__ __forceinline__ void gll16(const void* g, void* l){
  __builtin_amdgcn_global_load_lds(
    (const __attribute__((address_space(1))) unsigned int*)(unsigned long long)(size_t)g,
    (__attribute__((address_space(3))) unsigned int*)(unsigned int)(size_t)l,
    16, 0, 0);
}

// =====================================================================
// conv: W (qk|v|wg|proj -> Wcat layout) + x, fp32 -> bf16 into ws
__global__ void convk(const float* __restrict__ x,
                      const float* __restrict__ qk_w, const float* __restrict__ rev_v_w,
                      const float* __restrict__ wg_w, const float* __restrict__ proj_w,
                      u16* __restrict__ ws){
  long long i8 = ((long long)blockIdx.x * 256 + threadIdx.x) * 8;
  const float* s;
  if      (i8 <  524288) s = qk_w   + i8;
  else if (i8 <  786432) s = rev_v_w + (i8 - 524288);
  else if (i8 < 1310720) s = wg_w   + (i8 - 786432);
  else if (i8 < 1572864) s = proj_w + (i8 - 1310720);
  else                   s = x      + (i8 - 1572864);
  f32x4 lo = *(const f32x4*)s, hi = *(const f32x4*)(s + 4);
  short8 v;
  v[0]=f2bf(lo[0]); v[1]=f2bf(lo[1]); v[2]=f2bf(lo[2]); v[3]=f2bf(lo[3]);
  v[4]=f2bf(hi[0]); v[5]=f2bf(hi[1]); v[6]=f2bf(hi[2]); v[7]=f2bf(hi[3]);
  *(short8*)(ws + i8) = v;
}

// =====================================================================
// 256x256-tile 8-phase counted-vmcnt GEMM (derived schedule; R12: correct,
// ~= gemm128 speed, kept for smaller grid/tail).
template<int NT>
__global__ __launch_bounds__(512, 1)
void gemm256p(const u16* __restrict__ A,
              const u16* __restrict__ B,
              const float* __restrict__ b0, const float* __restrict__ b1,
              u16* __restrict__ Cg, int ldc){
  extern __shared__ __align__(16) unsigned char dyn[];
  const int tid = threadIdx.x, wave = tid >> 6, lane = tid & 63;
  const int l15 = lane & 15, lg = lane >> 4;
  const int nwg = gridDim.x, bidr = blockIdx.x;
  const int q8 = nwg >> 3, r8 = nwg & 7, xc = bidr & 7, oo = bidr >> 3;
  const int wg = (xc < r8 ? xc*(q8+1) : r8*(q8+1) + (xc-r8)*q8) + oo;
  const int bm = wg / NT, bn = wg % NT;
  const int wm = wave >> 2, wn = wave & 3;
  const f32x4 zf = {0.f, 0.f, 0.f, 0.f};

  float bia[4];
#pragma unroll
  for (int nf=0; nf<4; nf++){
    int n = bn*256 + wn*64 + nf*16 + l15;
    bia[nf] = (n < 1024) ? b0[n] : (n < 1536 ? b1[n-1024] : 0.f);
  }
  asm volatile("s_waitcnt vmcnt(0)" ::: "memory");

  const u16* Ab = A + (size_t)bm * 256 * 512;
  const u16* Bb = B + (size_t)bn * 256 * 512;

  const int c0 = tid, c1 = 512 + tid;
  const int r0s = c0 >> 3, sc0 = (c0 & 7) ^ (r0s & 7);
  const int r1s = c1 >> 3, sc1 = (c1 & 7) ^ (r1s & 7);

  auto stageA = [&](int t, int h){
    unsigned slot = ((unsigned)(t & 1)*2u + (unsigned)h) * 16384u;
    const u16* src = Ab + (size_t)(h*128) * 512 + t*64;
    gll16(src + (size_t)r0s*512 + sc0*8, dyn + slot + (unsigned)c0*16u);
    gll16(src + (size_t)r1s*512 + sc1*8, dyn + slot + (unsigned)c1*16u);
  };
  auto stageB = [&](int t, int h){
    unsigned slot = 65536u + ((unsigned)(t & 1)*2u + (unsigned)h) * 16384u;
    const u16* src = Bb + (size_t)(h*128) * 512 + t*64;
    gll16(src + (size_t)r0s*512 + sc0*8, dyn + slot + (unsigned)c0*16u);
    gll16(src + (size_t)r1s*512 + sc1*8, dyn + slot + (unsigned)c1*16u);
  };

  f32x4 acc[8][4];
#pragma unroll
  for (int mf=0; mf<8; mf++)
#pragma unroll
    for (int nf=0; nf<4; nf++) acc[mf][nf] = zf;

  stageA(0,0); stageA(0,1); stageB(0,0); stageB(0,1); stageB(1,0); stageB(1,1);
  asm volatile("s_waitcnt vmcnt(4)" ::: "memory");
  __builtin_amdgcn_s_barrier();
  __builtin_amdgcn_sched_barrier(0);

  short8 bq[4][2];
  for (int t = 0; t < 8; t++){
    const unsigned aslot = ((unsigned)(t&1)*2u + (unsigned)wm) * 16384u;
    const unsigned bslot = 65536u + ((unsigned)(t&1)*2u + (unsigned)(wn>>1)) * 16384u;
    const int brow = (wn & 1)*64;
#pragma unroll
    for (int p = 0; p < 4; p++){
      short8 aq[2][2];
#pragma unroll
      for (int j=0; j<2; j++)
#pragma unroll
        for (int kk=0; kk<2; kk++){
          int rl = p*32 + j*16 + l15;
          aq[j][kk] = *(const short8*)(dyn + aslot + (unsigned)rl*128u +
                        (((unsigned)(kk*64 + lg*16)) ^ (((unsigned)rl & 7u) << 4)));
        }
      if (p == 0){
#pragma unroll
        for (int nf=0; nf<4; nf++)
#pragma unroll
          for (int kk=0; kk<2; kk++){
            int rl = brow + nf*16 + l15;
            bq[nf][kk] = *(const short8*)(dyn + bslot + (unsigned)rl*128u +
                          (((unsigned)(kk*64 + lg*16)) ^ (((unsigned)rl & 7u) << 4)));
          }
      }
      if (p < 2){ if (t+1 < 8) stageA(t+1, p); }
      else      { if (t+2 < 8) stageB(t+2, p-2); }
      if (p == 3){
        if (t <= 5)      asm volatile("s_waitcnt vmcnt(4)" ::: "memory");
        else if (t == 6) asm volatile("s_waitcnt vmcnt(0)" ::: "memory");
      }
      __builtin_amdgcn_s_barrier();
      __builtin_amdgcn_sched_barrier(0);
      __builtin_amdgcn_s_setprio(1);
#pragma unroll
      for (int j=0; j<2; j++)
#pragma unroll
        for (int nf=0; nf<4; nf++)
#pragma unroll
          for (int kk=0; kk<2; kk++)
            acc[p*2+j][nf] = __builtin_amdgcn_mfma_f32_16x16x32_bf16(
                                aq[j][kk], bq[nf][kk], acc[p*2+j][nf], 0, 0, 0);
      __builtin_amdgcn_s_setprio(0);
      __builtin_amdgcn_s_barrier();
      __builtin_amdgcn_sched_barrier(0);
    }
  }

  __syncthreads();
#pragma unroll
  for (int mf=0; mf<8; mf++)
#pragma unroll
    for (int nf=0; nf<4; nf++)
#pragma unroll
      for (int i=0; i<4; i++){
        int row = wm*128 + mf*16 + lg*4 + i;
        unsigned colb = (unsigned)((wn*64 + nf*16 + l15) * 2);
        *(u16*)(dyn + (unsigned)row*512u + (colb ^ (((unsigned)row & 7u) << 4))) = f2bf(acc[mf][nf][i] + bia[nf]);
      }
  __syncthreads();
#pragma unroll
  for (int it=0; it<16; it++){
    int c = it*512 + tid;
    int r = c >> 5, cc = c & 31;
    short8 v = *(const short8*)(dyn + (unsigned)r*512u + (((unsigned)(cc*16)) ^ (((unsigned)r & 7u) << 4)));
    *(short8*)(Cg + (size_t)(bm*256 + r)*ldc + bn*256 + cc*8) = v;
  }
}

// =====================================================================
// 128x128-tile GEMM (m97 structure, proven 835 TF) — proj GEMM + fallback.
template<int NT, int F32OUT>
__global__ __launch_bounds__(256, 2)
void gemm128(const u16* __restrict__ A, int lda,
             const u16* __restrict__ B,
             const float* __restrict__ b0, const float* __restrict__ b1,
             void* __restrict__ Cg, int ldc){
  __shared__ __align__(16) unsigned char sm[32768];
  const int tid = threadIdx.x, wave = tid >> 6, lane = tid & 63;
  const int l15 = lane & 15, lg = lane >> 4;
  const int nwg = gridDim.x, bidr = blockIdx.x;
  const int q8 = nwg >> 3, r8 = nwg & 7, xc = bidr & 7, oo = bidr >> 3;
  const int wg = (xc < r8 ? xc * (q8 + 1) : r8 * (q8 + 1) + (xc - r8) * q8) + oo;
  const int bm = wg / NT, bn = wg % NT;
  const int wm = wave >> 1, wn = wave & 1;
  const f32x4 zf = {0.f, 0.f, 0.f, 0.f};
  f32x4 acc[4][4];
#pragma unroll
  for (int mt=0; mt<4; mt++)
#pragma unroll
    for (int nt=0; nt<4; nt++) acc[mt][nt] = zf;

  const u16* Ab = A + (size_t)bm * 128 * lda;
  const u16* Bb = B + (size_t)bn * 128 * 512;

  for (int ks = 0; ks < 8; ks++){
#pragma unroll
    for (int it = 0; it < 4; it++){
      int c = (wave*4 + it)*64 + lane;
      int r = c >> 3, cc = c & 7;
      int sc = cc ^ (r & 7);
      gll16(Ab + (size_t)r*lda + ks*64 + sc*8, sm + (unsigned)(wave*4 + it)*1024u);
      gll16(Bb + (size_t)r*512 + ks*64 + sc*8, sm + 16384u + (unsigned)(wave*4 + it)*1024u);
    }
    __syncthreads();
#pragma unroll
    for (int kk = 0; kk < 2; kk++){
      short8 aq[4], bq[4];
#pragma unroll
      for (int mt=0; mt<4; mt++){
        int r = wm*64 + mt*16 + l15;
        aq[mt] = *(const short8*)(sm + (unsigned)r*128u + (((unsigned)(kk*64 + lg*16)) ^ (((unsigned)r & 7u) << 4)));
      }
#pragma unroll
      for (int nt=0; nt<4; nt++){
        int r = wn*64 + nt*16 + l15;
        bq[nt] = *(const short8*)(sm + 16384u + (unsigned)r*128u + (((unsigned)(kk*64 + lg*16)) ^ (((unsigned)r & 7u) << 4)));
      }
#pragma unroll
      for (int mt=0; mt<4; mt++)
#pragma unroll
        for (int nt=0; nt<4; nt++)
          acc[mt][nt] = __builtin_amdgcn_mfma_f32_16x16x32_bf16(aq[mt], bq[nt], acc[mt][nt], 0, 0, 0);
    }
    __syncthreads();
  }

  float bia[4];
#pragma unroll
  for (int nt=0; nt<4; nt++){
    int n = bn*128 + wn*64 + nt*16 + l15;
    if (F32OUT) bia[nt] = b0[n];
    else        bia[nt] = (n < 1024) ? b0[n] : (n < 1536 ? b1[n - 1024] : 0.f);
  }

  if (!F32OUT){
#pragma unroll
    for (int mt=0; mt<4; mt++)
#pragma unroll
      for (int nt=0; nt<4; nt++)
#pragma unroll
        for (int i=0; i<4; i++){
          int row = wm*64 + mt*16 + lg*4 + i;
          unsigned colb = (unsigned)((wn*64 + nt*16 + l15) * 2);
          *(u16*)(sm + (unsigned)row*256u + (colb ^ (((unsigned)row & 7u) << 4))) = f2bf(acc[mt][nt][i] + bia[nt]);
        }
    __syncthreads();
    u16* Co = (u16*)Cg;
#pragma unroll
    for (int it=0; it<8; it++){
      int c = it*256 + tid;
      int r = c >> 4, cc = c & 15;
      short8 v = *(const short8*)(sm + (unsigned)r*256u + (((unsigned)(cc*16)) ^ (((unsigned)r & 7u) << 4)));
      *(short8*)(Co + (size_t)(bm*128 + r)*ldc + bn*128 + cc*8) = v;
    }
  } else {
    float* Co = (float*)Cg;
#pragma unroll
    for (int half=0; half<2; half++){
      if (wm == half){
#pragma unroll
        for (int mt=0; mt<4; mt++)
#pragma unroll
          for (int nt=0; nt<4; nt++)
#pragma unroll
            for (int i=0; i<4; i++){
              int row = mt*16 + lg*4 + i;
              unsigned colb = (unsigned)((wn*64 + nt*16 + l15) * 4);
              *(float*)(sm + (unsigned)row*512u + (colb ^ (((unsigned)row & 7u) << 4))) = acc[mt][nt][i] + bia[nt];
            }
      }
      __syncthreads();
#pragma unroll
      for (int it=0; it<8; it++){
        int c = it*256 + tid;
        int r = c >> 5, cc = c & 31;
        f32x4 v = *(const f32x4*)(sm + (unsigned)r*512u + (((unsigned)(cc*16)) ^ (((unsigned)r & 7u) << 4)));
        *(f32x4*)(Co + (size_t)(bm*128 + half*64 + r)*ldc + bn*128 + cc*4) = v;
      }
      __syncthreads();
    }
  }
}

// =====================================================================
// Attention half-window. block = (window, head-half). 8 waves, 1 head each.
// R13 changes vs R8: (1) q/k global loads issued FIRST (in flight under
// staging+barrier, T14); (2) rpb staged as FULL table with coalesced reads
// (was a stride-16 scalar gather). LDS: V-half 25088 | PT 50176 | RPB 5408
// = 80672 B <= 81920 -> still 2 blocks/CU.
__global__ __launch_bounds__(512, 4)
void attn_half(const u16* __restrict__ qkv, const float* __restrict__ rpb,
               u16* __restrict__ em){
  __shared__ __align__(16) unsigned char lds[80672];
  const unsigned L_V = 0u, L_PT = 25088u, L_RPB = 75264u;
  const int tid = threadIdx.x, wave = tid >> 6, lane = tid & 63;
  const int l15 = lane & 15, lg = lane >> 4;
  const int bid = blockIdx.x, win = bid >> 1, hf = bid & 1;
  const u16* base = qkv + (size_t)win * 49 * 2560;
  u16* emb = em + (size_t)win * 49 * 512 + hf * 256;
  unsigned char* ptb = lds + L_PT + (unsigned)wave * 6272u;
  const int h = hf*8 + wave;
  const f32x4 zf = {0.f, 0.f, 0.f, 0.f};

  // ---- issue q/k fragment loads FIRST: they fly under the staging below
  short8 aq[4], bq[4];
#pragma unroll
  for (int mt=0; mt<4; mt++){
    int r = mt*16 + l15; if (r > 48) r = 48;
    aq[mt] = *(const short8*)(base + (size_t)r*2560 + h*32 + lg*8);
  }
#pragma unroll
  for (int nt=0; nt<4; nt++){
    int kt = nt*16 + l15; if (kt > 48) kt = 48;
    bq[nt] = *(const short8*)(base + (size_t)kt*2560 + 512 + h*32 + lg*8);
  }

  // ---- stage full rpb table (coalesced contiguous f32 reads) + V half
  for (int i = tid; i < 2704; i += 512)
    *(u16*)(lds + L_RPB + i*2) = f2bf(rpb[i]);
  for (int c = tid; c < 49*32; c += 512){
    int r = c >> 5, c8 = c & 31;
    short8 v = *(const short8*)(base + (size_t)r*2560 + 1024 + hf*256 + c8*8);
    *(short8*)(lds + swz(L_V, r, 512u, (unsigned)(c8*16))) = v;
  }
  __syncthreads();

  // S = q @ k^T for head h
  f32x4 s[4][4];
#pragma unroll
  for (int mt=0; mt<4; mt++)
#pragma unroll
    for (int nt=0; nt<4; nt++) s[mt][nt] = zf;
#pragma unroll
  for (int mt=0; mt<4; mt++)
#pragma unroll
    for (int nt=0; nt<4; nt++)
      s[mt][nt] = __builtin_amdgcn_mfma_f32_16x16x32_bf16(aq[mt], bq[nt], s[mt][nt], 0, 0, 0);
  // scale + rel-pos bias + mask padded keys
#pragma unroll
  for (int mt=0; mt<4; mt++)
#pragma unroll
    for (int nt=0; nt<4; nt++)
#pragma unroll
      for (int i=0; i<4; i++){
        int q  = mt*16 + lg*4 + i;
        int kt = nt*16 + l15;
        float v = s[mt][nt][i] * SCALE_F;
        if (kt < 49){
          int qc = (q > 48) ? 48 : q;
          int qi = qc / 7, qj = qc - qi*7;
          int ki = kt / 7, kj = kt - ki*7;
          int idx = (qi - ki + 6)*13 + (qj - kj + 6);
          v += bf2f(*(const u16*)(lds + L_RPB + (idx*16 + h)*2));
        } else v = -1e30f;
        s[mt][nt][i] = v;
      }
  // wave-parallel softmax over key dim
#pragma unroll
  for (int mt=0; mt<4; mt++)
#pragma unroll
    for (int i=0; i<4; i++){
      float m = fmaxf(fmaxf(s[mt][0][i], s[mt][1][i]), fmaxf(s[mt][2][i], s[mt][3][i]));
      m = fmaxf(m, __shfl_xor(m, 1)); m = fmaxf(m, __shfl_xor(m, 2));
      m = fmaxf(m, __shfl_xor(m, 4)); m = fmaxf(m, __shfl_xor(m, 8));
      float sum = 0.f;
#pragma unroll
      for (int nt=0; nt<4; nt++){ float e = __expf(s[mt][nt][i] - m); s[mt][nt][i] = e; sum += e; }
      sum += __shfl_xor(sum, 1); sum += __shfl_xor(sum, 2);
      sum += __shfl_xor(sum, 4); sum += __shfl_xor(sum, 8);
      float inv = 1.0f / sum;
#pragma unroll
      for (int nt=0; nt<4; nt++) s[mt][nt][i] *= inv;
    }
  // store P transposed (PT[kt][q]); zero padded q
#pragma unroll
  for (int mt=0; mt<4; mt++)
#pragma unroll
    for (int nt=0; nt<4; nt++)
#pragma unroll
      for (int i=0; i<4; i++){
        int q  = mt*16 + lg*4 + i;
        int kt = nt*16 + l15;
        if (kt < 49){
          u16 val = (q < 49) ? f2bf(s[mt][nt][i]) : (u16)0;
          *(u16*)(ptb + (unsigned)kt*128u + (((unsigned)(q*2)) ^ (((unsigned)kt & 7u) << 4))) = val;
        }
      }
  // em = PT-as-A @ V_head (V from half-staged LDS; local ch = wave*32 + ...)
  f32x4 emv[4][2];
#pragma unroll
  for (int mt=0; mt<4; mt++)
#pragma unroll
    for (int nt=0; nt<2; nt++) emv[mt][nt] = zf;
#pragma unroll
  for (int kk=0; kk<2; kk++){
    short8 pa[4];
#pragma unroll
    for (int mt=0; mt<4; mt++){
      int r = mt*16 + l15; if (r > 48) r = 48;
      pa[mt] = *(const short8*)(ptb + (unsigned)r*128u + (((unsigned)(kk*64 + lg*16)) ^ (((unsigned)r & 7u) << 4)));
    }
    short8 vb[2];
#pragma unroll
    for (int nt=0; nt<2; nt++){
      int chl = wave*32 + nt*16 + l15;
#pragma unroll
      for (int j=0; j<8; j++){
        int kt = kk*32 + lg*8 + j; if (kt > 48) kt = 48;
        vb[nt][j] = *(const short*)(lds + swz(L_V, kt, 512u, (unsigned)(chl*2)));
      }
    }
#pragma unroll
    for (int mt=0; mt<4; mt++)
#pragma unroll
      for (int nt=0; nt<2; nt++)
        emv[mt][nt] = __builtin_amdgcn_mfma_f32_16x16x32_bf16(pa[mt], vb[nt], emv[mt][nt], 0, 0, 0);
  }
#pragma unroll
  for (int mt=0; mt<4; mt++)
#pragma unroll
    for (int nt=0; nt<2; nt++)
#pragma unroll
      for (int i=0; i<4; i++){
        int q = mt*16 + lg*4 + i;
        if (q < 49)
          emb[(size_t)q*512 + wave*32 + nt*16 + l15] = f2bf(emv[mt][nt][i]);
      }
}

// =====================================================================
// Hypernet (R8 structure, proven; at memory floor): per token t (one per wave).
__global__ __launch_bounds__(512, 4)
void hyper2(const u16* __restrict__ qkvpw, const u16* __restrict__ em,
            u16* __restrict__ o1){
  __shared__ __align__(16) unsigned char lds[16384];
  const int tid = threadIdx.x, wave = tid >> 6, lane = tid & 63;
  const int l15 = lane & 15, lg = lane >> 4;
  unsigned char* pwb = lds + (unsigned)wave * 2048u;
  const size_t t = (size_t)blockIdx.x * 8 + wave;
  const u16* pwt = qkvpw + t*2560 + 1536;
  const u16* emt = em + t*512;
  const f32x4 zf = {0.f, 0.f, 0.f, 0.f};

#pragma unroll
  for (int rd = 0; rd < 2; rd++){
    int i8 = (rd*64 + lane)*8;
    short8 v = *(const short8*)(pwt + i8);
    int e = i8 >> 5, f0 = i8 & 31;
#pragma unroll
    for (int jj = 0; jj < 8; jj++){
      int f = f0 + jj;
      *(u16*)(pwb + (unsigned)f*64u + (((unsigned)(e*2)) ^ (((unsigned)f & 3u) << 4))) = (u16)v[jj];
    }
  }
  short8 ea = *(const short8*)(emt + l15*32 + lg*8);
  __syncthreads();
  f32x4 o[2];
#pragma unroll
  for (int nt=0; nt<2; nt++){
    int f = nt*16 + l15;
    short8 pb = *(const short8*)(pwb + (unsigned)f*64u + (((unsigned)(lg*16)) ^ (((unsigned)f & 3u) << 4)));
    o[nt] = __builtin_amdgcn_mfma_f32_16x16x32_bf16(ea, pb, zf, 0, 0, 0);
  }
  __syncthreads();
#pragma unroll
  for (int nt=0; nt<2; nt++)
#pragma unroll
    for (int i=0; i<4; i++){
      int ch = (lg*4 + i)*32 + nt*16 + l15;
      *(u16*)(pwb + (unsigned)ch*2u) = f2bf(o[nt][i]);
    }
  __syncthreads();
  short8 v = *(const short8*)(pwb + (unsigned)lane*16u);
  *(short8*)(o1 + t*512 + lane*8) = v;
}

// =====================================================================
extern "C" void kernel_launch(void* const* d_in, const int* in_sizes, int n_in,
                              void* d_out, int out_size, void* d_ws, size_t ws_size,
                              hipStream_t stream){
  const float* x       = (const float*)d_in[0];
  const float* qk_w    = (const float*)d_in[1];
  const float* qk_b    = (const float*)d_in[2];
  const float* rev_v_w = (const float*)d_in[3];
  const float* rev_v_b = (const float*)d_in[4];
  const float* wg_w    = (const float*)d_in[5];
  const float* proj_w  = (const float*)d_in[6];
  const float* proj_b  = (const float*)d_in[7];
  const float* rpb     = (const float*)d_in[8];
  u16* ws = (u16*)d_ws;

  const unsigned long long BASE = 105906176ULL;   // Wcat + Wproj + xb
  // per-window chunk: (qkvpw 2560 + o1 512) el * 49 * 2B = 301056.
  // em aliases the xb chunk region (dead after main GEMM of that chunk).
  int C = 0;
  for (int cand : {2048, 1024, 512, 256, 128}){
    if (BASE + (unsigned long long)cand * 301056ULL <= ws_size){ C = cand; break; }
  }
  if (C == 0) return;

  u16* Wcat  = ws;
  u16* Wproj = ws + 1310720;
  u16* xb    = ws + 1572864;
  u16* qkvpw = ws + 52953088ULL;
  u16* o1    = qkvpw + (size_t)C * 49 * 2560;

  convk<<<25856, 256, 0, stream>>>(x, qk_w, rev_v_w, wg_w, proj_w, ws);

  bool use256 = ((C * 49) % 256 == 0);
  if (use256){
    hipError_t e = hipFuncSetAttribute((const void*)gemm256p<10>,
        hipFuncAttributeMaxDynamicSharedMemorySize, 131072);
    if (e != hipSuccess) use256 = false;
  }

  const int nch = 2048 / C;
  const int mt128 = C * 49 / 128;
  const int mt256 = C * 49 / 256;
  for (int ch = 0; ch < nch; ch++){
    size_t t0 = (size_t)ch * C * 49;
    u16* em = xb + t0 * 512;            // alias: xb chunk is dead after main GEMM
    if (use256)
      gemm256p<10><<<mt256 * 10, 512, 131072, stream>>>(xb + t0*512, Wcat,
          qk_b, rev_v_b, qkvpw, 2560);
    else
      gemm128<20, 0><<<mt128 * 20, 256, 0, stream>>>(xb + t0*512, 512, Wcat,
          qk_b, rev_v_b, qkvpw, 2560);
    attn_half<<<2 * C, 512, 0, stream>>>(qkvpw, rpb, em);
    hyper2<<<C * 49 / 8, 512, 0, stream>>>(qkvpw, em, o1);
    gemm128<4, 1><<<mt128 * 4, 256, 0, stream>>>(o1, 512, Wproj,
        proj_b, (const float*)nullptr, (float*)d_out + t0*512, 512);
  }
  (void)Wcat; (void)Wproj;
}

// Round 15
// 656.913 us; speedup vs baseline: 1.0322x; 1.0322x over previous
//
#include <hip/hip_runtime.h>
#include <hip/hip_bf16.h>
#include <stdint.h>

typedef __attribute__((ext_vector_type(8))) short short8;
typedef __attribute__((ext_vector_type(4))) float f32x4;
typedef unsigned short u16;

#define SCALE_F 0.17677669529663687f

__device__ __forceinline__ u16 f2bf(float f){
  union { float f; unsigned u; } x; x.f = f;
  unsigned r = x.u + 0x7fffu + ((x.u >> 16) & 1u);
  return (u16)(r >> 16);
}
__device__ __forceinline__ float bf2f(u16 u){
  union { float f; unsigned u; } x; x.u = ((unsigned)u) << 16; return x.f;
}
// XOR-swizzled LDS byte address within a row (rowb bytes/row)
__device__ __forceinline__ unsigned swz(unsigned base, int row, unsigned rowb, unsigned colb){
  return base + (unsigned)row * rowb + (colb ^ (((unsigned)row & 7u) << 4));
}
// async global->LDS 16B
__device__ __forceinline__ void gll16(const void* g, void* l){
  __builtin_amdgcn_global_load_lds(
    (const __attribute__((address_space(1))) unsigned int*)(unsigned long long)(size_t)g,
    (__attribute__((address_space(3))) unsigned int*)(unsigned int)(size_t)l,
    16, 0, 0);
}

// =====================================================================
// conv: W (qk|v|wg|proj -> Wcat layout) + x, fp32 -> bf16 into ws
__global__ void convk(const float* __restrict__ x,
                      const float* __restrict__ qk_w, const float* __restrict__ rev_v_w,
                      const float* __restrict__ wg_w, const float* __restrict__ proj_w,
                      u16* __restrict__ ws){
  long long i8 = ((long long)blockIdx.x * 256 + threadIdx.x) * 8;
  const float* s;
  if      (i8 <  524288) s = qk_w   + i8;
  else if (i8 <  786432) s = rev_v_w + (i8 - 524288);
  else if (i8 < 1310720) s = wg_w   + (i8 - 786432);
  else if (i8 < 1572864) s = proj_w + (i8 - 1310720);
  else                   s = x      + (i8 - 1572864);
  f32x4 lo = *(const f32x4*)s, hi = *(const f32x4*)(s + 4);
  short8 v;
  v[0]=f2bf(lo[0]); v[1]=f2bf(lo[1]); v[2]=f2bf(lo[2]); v[3]=f2bf(lo[3]);
  v[4]=f2bf(hi[0]); v[5]=f2bf(hi[1]); v[6]=f2bf(hi[2]); v[7]=f2bf(hi[3]);
  *(short8*)(ws + i8) = v;
}

// =====================================================================
// 256x256-tile 8-phase counted-vmcnt GEMM (derived schedule; R12: correct,
// ~= gemm128 speed, kept for smaller grid/tail).
template<int NT>
__global__ __launch_bounds__(512, 1)
void gemm256p(const u16* __restrict__ A,
              const u16* __restrict__ B,
              const float* __restrict__ b0, const float* __restrict__ b1,
              u16* __restrict__ Cg, int ldc){
  extern __shared__ __align__(16) unsigned char dyn[];
  const int tid = threadIdx.x, wave = tid >> 6, lane = tid & 63;
  const int l15 = lane & 15, lg = lane >> 4;
  const int nwg = gridDim.x, bidr = blockIdx.x;
  const int q8 = nwg >> 3, r8 = nwg & 7, xc = bidr & 7, oo = bidr >> 3;
  const int wg = (xc < r8 ? xc*(q8+1) : r8*(q8+1) + (xc-r8)*q8) + oo;
  const int bm = wg / NT, bn = wg % NT;
  const int wm = wave >> 2, wn = wave & 3;
  const f32x4 zf = {0.f, 0.f, 0.f, 0.f};

  float bia[4];
#pragma unroll
  for (int nf=0; nf<4; nf++){
    int n = bn*256 + wn*64 + nf*16 + l15;
    bia[nf] = (n < 1024) ? b0[n] : (n < 1536 ? b1[n-1024] : 0.f);
  }
  asm volatile("s_waitcnt vmcnt(0)" ::: "memory");

  const u16* Ab = A + (size_t)bm * 256 * 512;
  const u16* Bb = B + (size_t)bn * 256 * 512;

  const int c0 = tid, c1 = 512 + tid;
  const int r0s = c0 >> 3, sc0 = (c0 & 7) ^ (r0s & 7);
  const int r1s = c1 >> 3, sc1 = (c1 & 7) ^ (r1s & 7);

  auto stageA = [&](int t, int h){
    unsigned slot = ((unsigned)(t & 1)*2u + (unsigned)h) * 16384u;
    const u16* src = Ab + (size_t)(h*128) * 512 + t*64;
    gll16(src + (size_t)r0s*512 + sc0*8, dyn + slot + (unsigned)c0*16u);
    gll16(src + (size_t)r1s*512 + sc1*8, dyn + slot + (unsigned)c1*16u);
  };
  auto stageB = [&](int t, int h){
    unsigned slot = 65536u + ((unsigned)(t & 1)*2u + (unsigned)h) * 16384u;
    const u16* src = Bb + (size_t)(h*128) * 512 + t*64;
    gll16(src + (size_t)r0s*512 + sc0*8, dyn + slot + (unsigned)c0*16u);
    gll16(src + (size_t)r1s*512 + sc1*8, dyn + slot + (unsigned)c1*16u);
  };

  f32x4 acc[8][4];
#pragma unroll
  for (int mf=0; mf<8; mf++)
#pragma unroll
    for (int nf=0; nf<4; nf++) acc[mf][nf] = zf;

  stageA(0,0); stageA(0,1); stageB(0,0); stageB(0,1); stageB(1,0); stageB(1,1);
  asm volatile("s_waitcnt vmcnt(4)" ::: "memory");
  __builtin_amdgcn_s_barrier();
  __builtin_amdgcn_sched_barrier(0);

  short8 bq[4][2];
  for (int t = 0; t < 8; t++){
    const unsigned aslot = ((unsigned)(t&1)*2u + (unsigned)wm) * 16384u;
    const unsigned bslot = 65536u + ((unsigned)(t&1)*2u + (unsigned)(wn>>1)) * 16384u;
    const int brow = (wn & 1)*64;
#pragma unroll
    for (int p = 0; p < 4; p++){
      short8 aq[2][2];
#pragma unroll
      for (int j=0; j<2; j++)
#pragma unroll
        for (int kk=0; kk<2; kk++){
          int rl = p*32 + j*16 + l15;
          aq[j][kk] = *(const short8*)(dyn + aslot + (unsigned)rl*128u +
                        (((unsigned)(kk*64 + lg*16)) ^ (((unsigned)rl & 7u) << 4)));
        }
      if (p == 0){
#pragma unroll
        for (int nf=0; nf<4; nf++)
#pragma unroll
          for (int kk=0; kk<2; kk++){
            int rl = brow + nf*16 + l15;
            bq[nf][kk] = *(const short8*)(dyn + bslot + (unsigned)rl*128u +
                          (((unsigned)(kk*64 + lg*16)) ^ (((unsigned)rl & 7u) << 4)));
          }
      }
      if (p < 2){ if (t+1 < 8) stageA(t+1, p); }
      else      { if (t+2 < 8) stageB(t+2, p-2); }
      if (p == 3){
        if (t <= 5)      asm volatile("s_waitcnt vmcnt(4)" ::: "memory");
        else if (t == 6) asm volatile("s_waitcnt vmcnt(0)" ::: "memory");
      }
      __builtin_amdgcn_s_barrier();
      __builtin_amdgcn_sched_barrier(0);
      __builtin_amdgcn_s_setprio(1);
#pragma unroll
      for (int j=0; j<2; j++)
#pragma unroll
        for (int nf=0; nf<4; nf++)
#pragma unroll
          for (int kk=0; kk<2; kk++)
            acc[p*2+j][nf] = __builtin_amdgcn_mfma_f32_16x16x32_bf16(
                                aq[j][kk], bq[nf][kk], acc[p*2+j][nf], 0, 0, 0);
      __builtin_amdgcn_s_setprio(0);
      __builtin_amdgcn_s_barrier();
      __builtin_amdgcn_sched_barrier(0);
    }
  }

  __syncthreads();
#pragma unroll
  for (int mf=0; mf<8; mf++)
#pragma unroll
    for (int nf=0; nf<4; nf++)
#pragma unroll
      for (int i=0; i<4; i++){
        int row = wm*128 + mf*16 + lg*4 + i;
        unsigned colb = (unsigned)((wn*64 + nf*16 + l15) * 2);
        *(u16*)(dyn + (unsigned)row*512u + (colb ^ (((unsigned)row & 7u) << 4))) = f2bf(acc[mf][nf][i] + bia[nf]);
      }
  __syncthreads();
#pragma unroll
  for (int it=0; it<16; it++){
    int c = it*512 + tid;
    int r = c >> 5, cc = c & 31;
    short8 v = *(const short8*)(dyn + (unsigned)r*512u + (((unsigned)(cc*16)) ^ (((unsigned)r & 7u) << 4)));
    *(short8*)(Cg + (size_t)(bm*256 + r)*ldc + bn*256 + cc*8) = v;
  }
}

// =====================================================================
// 128x128-tile GEMM (m97 structure, proven 835 TF) — proj GEMM + fallback.
template<int NT, int F32OUT>
__global__ __launch_bounds__(256, 2)
void gemm128(const u16* __restrict__ A, int lda,
             const u16* __restrict__ B,
             const float* __restrict__ b0, const float* __restrict__ b1,
             void* __restrict__ Cg, int ldc){
  __shared__ __align__(16) unsigned char sm[32768];
  const int tid = threadIdx.x, wave = tid >> 6, lane = tid & 63;
  const int l15 = lane & 15, lg = lane >> 4;
  const int nwg = gridDim.x, bidr = blockIdx.x;
  const int q8 = nwg >> 3, r8 = nwg & 7, xc = bidr & 7, oo = bidr >> 3;
  const int wg = (xc < r8 ? xc * (q8 + 1) : r8 * (q8 + 1) + (xc - r8) * q8) + oo;
  const int bm = wg / NT, bn = wg % NT;
  const int wm = wave >> 1, wn = wave & 1;
  const f32x4 zf = {0.f, 0.f, 0.f, 0.f};
  f32x4 acc[4][4];
#pragma unroll
  for (int mt=0; mt<4; mt++)
#pragma unroll
    for (int nt=0; nt<4; nt++) acc[mt][nt] = zf;

  const u16* Ab = A + (size_t)bm * 128 * lda;
  const u16* Bb = B + (size_t)bn * 128 * 512;

  for (int ks = 0; ks < 8; ks++){
#pragma unroll
    for (int it = 0; it < 4; it++){
      int c = (wave*4 + it)*64 + lane;
      int r = c >> 3, cc = c & 7;
      int sc = cc ^ (r & 7);
      gll16(Ab + (size_t)r*lda + ks*64 + sc*8, sm + (unsigned)(wave*4 + it)*1024u);
      gll16(Bb + (size_t)r*512 + ks*64 + sc*8, sm + 16384u + (unsigned)(wave*4 + it)*1024u);
    }
    __syncthreads();
#pragma unroll
    for (int kk = 0; kk < 2; kk++){
      short8 aq[4], bq[4];
#pragma unroll
      for (int mt=0; mt<4; mt++){
        int r = wm*64 + mt*16 + l15;
        aq[mt] = *(const short8*)(sm + (unsigned)r*128u + (((unsigned)(kk*64 + lg*16)) ^ (((unsigned)r & 7u) << 4)));
      }
#pragma unroll
      for (int nt=0; nt<4; nt++){
        int r = wn*64 + nt*16 + l15;
        bq[nt] = *(const short8*)(sm + 16384u + (unsigned)r*128u + (((unsigned)(kk*64 + lg*16)) ^ (((unsigned)r & 7u) << 4)));
      }
#pragma unroll
      for (int mt=0; mt<4; mt++)
#pragma unroll
        for (int nt=0; nt<4; nt++)
          acc[mt][nt] = __builtin_amdgcn_mfma_f32_16x16x32_bf16(aq[mt], bq[nt], acc[mt][nt], 0, 0, 0);
    }
    __syncthreads();
  }

  float bia[4];
#pragma unroll
  for (int nt=0; nt<4; nt++){
    int n = bn*128 + wn*64 + nt*16 + l15;
    if (F32OUT) bia[nt] = b0[n];
    else        bia[nt] = (n < 1024) ? b0[n] : (n < 1536 ? b1[n - 1024] : 0.f);
  }

  if (!F32OUT){
#pragma unroll
    for (int mt=0; mt<4; mt++)
#pragma unroll
      for (int nt=0; nt<4; nt++)
#pragma unroll
        for (int i=0; i<4; i++){
          int row = wm*64 + mt*16 + lg*4 + i;
          unsigned colb = (unsigned)((wn*64 + nt*16 + l15) * 2);
          *(u16*)(sm + (unsigned)row*256u + (colb ^ (((unsigned)row & 7u) << 4))) = f2bf(acc[mt][nt][i] + bia[nt]);
        }
    __syncthreads();
    u16* Co = (u16*)Cg;
#pragma unroll
    for (int it=0; it<8; it++){
      int c = it*256 + tid;
      int r = c >> 4, cc = c & 15;
      short8 v = *(const short8*)(sm + (unsigned)r*256u + (((unsigned)(cc*16)) ^ (((unsigned)r & 7u) << 4)));
      *(short8*)(Co + (size_t)(bm*128 + r)*ldc + bn*128 + cc*8) = v;
    }
  } else {
    float* Co = (float*)Cg;
#pragma unroll
    for (int half=0; half<2; half++){
      if (wm == half){
#pragma unroll
        for (int mt=0; mt<4; mt++)
#pragma unroll
          for (int nt=0; nt<4; nt++)
#pragma unroll
            for (int i=0; i<4; i++){
              int row = mt*16 + lg*4 + i;
              unsigned colb = (unsigned)((wn*64 + nt*16 + l15) * 4);
              *(float*)(sm + (unsigned)row*512u + (colb ^ (((unsigned)row & 7u) << 4))) = acc[mt][nt][i] + bia[nt];
            }
      }
      __syncthreads();
#pragma unroll
      for (int it=0; it<8; it++){
        int c = it*256 + tid;
        int r = c >> 5, cc = c & 31;
        f32x4 v = *(const f32x4*)(sm + (unsigned)r*512u + (((unsigned)(cc*16)) ^ (((unsigned)r & 7u) << 4)));
        *(f32x4*)(Co + (size_t)(bm*128 + half*64 + r)*ldc + bn*128 + cc*4) = v;
      }
      __syncthreads();
    }
  }
}

// =====================================================================
// Attention half-window (R8 structure, measured best). block = (window, head-half).
__global__ __launch_bounds__(512, 4)
void attn_half(const u16* __restrict__ qkv, const float* __restrict__ rpb,
               u16* __restrict__ em){
  __shared__ __align__(16) unsigned char lds[77968];
  const unsigned L_V = 0u, L_PT = 25088u, L_RPB = 75264u;
  const int tid = threadIdx.x, wave = tid >> 6, lane = tid & 63;
  const int l15 = lane & 15, lg = lane >> 4;
  const int bid = blockIdx.x, win = bid >> 1, hf = bid & 1;
  const u16* base = qkv + (size_t)win * 49 * 2560;
  u16* emb = em + (size_t)win * 49 * 512 + hf * 256;
  unsigned char* ptb = lds + L_PT + (unsigned)wave * 6272u;
  const int h = hf*8 + wave;
  const f32x4 zf = {0.f, 0.f, 0.f, 0.f};

  for (int i = tid; i < 169*8; i += 512){
    int idx = i >> 3, hh = i & 7;
    *(u16*)(lds + L_RPB + i*2) = f2bf(rpb[idx*16 + hf*8 + hh]);
  }
  for (int c = tid; c < 49*32; c += 512){
    int r = c >> 5, c8 = c & 31;
    short8 v = *(const short8*)(base + (size_t)r*2560 + 1024 + hf*256 + c8*8);
    *(short8*)(lds + swz(L_V, r, 512u, (unsigned)(c8*16))) = v;
  }
  __syncthreads();

  short8 aq[4], bq[4];
#pragma unroll
  for (int mt=0; mt<4; mt++){
    int r = mt*16 + l15; if (r > 48) r = 48;
    aq[mt] = *(const short8*)(base + (size_t)r*2560 + h*32 + lg*8);
  }
#pragma unroll
  for (int nt=0; nt<4; nt++){
    int kt = nt*16 + l15; if (kt > 48) kt = 48;
    bq[nt] = *(const short8*)(base + (size_t)kt*2560 + 512 + h*32 + lg*8);
  }
  f32x4 s[4][4];
#pragma unroll
  for (int mt=0; mt<4; mt++)
#pragma unroll
    for (int nt=0; nt<4; nt++) s[mt][nt] = zf;
#pragma unroll
  for (int mt=0; mt<4; mt++)
#pragma unroll
    for (int nt=0; nt<4; nt++)
      s[mt][nt] = __builtin_amdgcn_mfma_f32_16x16x32_bf16(aq[mt], bq[nt], s[mt][nt], 0, 0, 0);
#pragma unroll
  for (int mt=0; mt<4; mt++)
#pragma unroll
    for (int nt=0; nt<4; nt++)
#pragma unroll
      for (int i=0; i<4; i++){
        int q  = mt*16 + lg*4 + i;
        int kt = nt*16 + l15;
        float v = s[mt][nt][i] * SCALE_F;
        if (kt < 49){
          int qc = (q > 48) ? 48 : q;
          int qi = qc / 7, qj = qc - qi*7;
          int ki = kt / 7, kj = kt - ki*7;
          int idx = (qi - ki + 6)*13 + (qj - kj + 6);
          v += bf2f(*(const u16*)(lds + L_RPB + (idx*8 + wave)*2));
        } else v = -1e30f;
        s[mt][nt][i] = v;
      }
#pragma unroll
  for (int mt=0; mt<4; mt++)
#pragma unroll
    for (int i=0; i<4; i++){
      float m = fmaxf(fmaxf(s[mt][0][i], s[mt][1][i]), fmaxf(s[mt][2][i], s[mt][3][i]));
      m = fmaxf(m, __shfl_xor(m, 1)); m = fmaxf(m, __shfl_xor(m, 2));
      m = fmaxf(m, __shfl_xor(m, 4)); m = fmaxf(m, __shfl_xor(m, 8));
      float sum = 0.f;
#pragma unroll
      for (int nt=0; nt<4; nt++){ float e = __expf(s[mt][nt][i] - m); s[mt][nt][i] = e; sum += e; }
      sum += __shfl_xor(sum, 1); sum += __shfl_xor(sum, 2);
      sum += __shfl_xor(sum, 4); sum += __shfl_xor(sum, 8);
      float inv = 1.0f / sum;
#pragma unroll
      for (int nt=0; nt<4; nt++) s[mt][nt][i] *= inv;
    }
#pragma unroll
  for (int mt=0; mt<4; mt++)
#pragma unroll
    for (int nt=0; nt<4; nt++)
#pragma unroll
      for (int i=0; i<4; i++){
        int q  = mt*16 + lg*4 + i;
        int kt = nt*16 + l15;
        if (kt < 49){
          u16 val = (q < 49) ? f2bf(s[mt][nt][i]) : (u16)0;
          *(u16*)(ptb + (unsigned)kt*128u + (((unsigned)(q*2)) ^ (((unsigned)kt & 7u) << 4))) = val;
        }
      }
  f32x4 emv[4][2];
#pragma unroll
  for (int mt=0; mt<4; mt++)
#pragma unroll
    for (int nt=0; nt<2; nt++) emv[mt][nt] = zf;
#pragma unroll
  for (int kk=0; kk<2; kk++){
    short8 pa[4];
#pragma unroll
    for (int mt=0; mt<4; mt++){
      int r = mt*16 + l15; if (r > 48) r = 48;
      pa[mt] = *(const short8*)(ptb + (unsigned)r*128u + (((unsigned)(kk*64 + lg*16)) ^ (((unsigned)r & 7u) << 4)));
    }
    short8 vb[2];
#pragma unroll
    for (int nt=0; nt<2; nt++){
      int chl = wave*32 + nt*16 + l15;
#pragma unroll
      for (int j=0; j<8; j++){
        int kt = kk*32 + lg*8 + j; if (kt > 48) kt = 48;
        vb[nt][j] = *(const short*)(lds + swz(L_V, kt, 512u, (unsigned)(chl*2)));
      }
    }
#pragma unroll
    for (int mt=0; mt<4; mt++)
#pragma unroll
      for (int nt=0; nt<2; nt++)
        emv[mt][nt] = __builtin_amdgcn_mfma_f32_16x16x32_bf16(pa[mt], vb[nt], emv[mt][nt], 0, 0, 0);
  }
#pragma unroll
  for (int mt=0; mt<4; mt++)
#pragma unroll
    for (int nt=0; nt<2; nt++)
#pragma unroll
      for (int i=0; i<4; i++){
        int q = mt*16 + lg*4 + i;
        if (q < 49)
          emb[(size_t)q*512 + wave*32 + nt*16 + l15] = f2bf(emv[mt][nt][i]);
      }
}

// =====================================================================
// Hypernet (R8 structure, proven; at memory floor): per token t (one per wave).
__global__ __launch_bounds__(512, 4)
void hyper2(const u16* __restrict__ qkvpw, const u16* __restrict__ em,
            u16* __restrict__ o1){
  __shared__ __align__(16) unsigned char lds[16384];
  const int tid = threadIdx.x, wave = tid >> 6, lane = tid & 63;
  const int l15 = lane & 15, lg = lane >> 4;
  unsigned char* pwb = lds + (unsigned)wave * 2048u;
  const size_t t = (size_t)blockIdx.x * 8 + wave;
  const u16* pwt = qkvpw + t*2560 + 1536;
  const u16* emt = em + t*512;
  const f32x4 zf = {0.f, 0.f, 0.f, 0.f};

#pragma unroll
  for (int rd = 0; rd < 2; rd++){
    int i8 = (rd*64 + lane)*8;
    short8 v = *(const short8*)(pwt + i8);
    int e = i8 >> 5, f0 = i8 & 31;
#pragma unroll
    for (int jj = 0; jj < 8; jj++){
      int f = f0 + jj;
      *(u16*)(pwb + (unsigned)f*64u + (((unsigned)(e*2)) ^ (((unsigned)f & 3u) << 4))) = (u16)v[jj];
    }
  }
  short8 ea = *(const short8*)(emt + l15*32 + lg*8);
  __syncthreads();
  f32x4 o[2];
#pragma unroll
  for (int nt=0; nt<2; nt++){
    int f = nt*16 + l15;
    short8 pb = *(const short8*)(pwb + (unsigned)f*64u + (((unsigned)(lg*16)) ^ (((unsigned)f & 3u) << 4)));
    o[nt] = __builtin_amdgcn_mfma_f32_16x16x32_bf16(ea, pb, zf, 0, 0, 0);
  }
  __syncthreads();
#pragma unroll
  for (int nt=0; nt<2; nt++)
#pragma unroll
    for (int i=0; i<4; i++){
      int ch = (lg*4 + i)*32 + nt*16 + l15;
      *(u16*)(pwb + (unsigned)ch*2u) = f2bf(o[nt][i]);
    }
  __syncthreads();
  short8 v = *(const short8*)(pwb + (unsigned)lane*16u);
  *(short8*)(o1 + t*512 + lane*8) = v;
}

// =====================================================================
extern "C" void kernel_launch(void* const* d_in, const int* in_sizes, int n_in,
                              void* d_out, int out_size, void* d_ws, size_t ws_size,
                              hipStream_t stream){
  const float* x       = (const float*)d_in[0];
  const float* qk_w    = (const float*)d_in[1];
  const float* qk_b    = (const float*)d_in[2];
  const float* rev_v_w = (const float*)d_in[3];
  const float* rev_v_b = (const float*)d_in[4];
  const float* wg_w    = (const float*)d_in[5];
  const float* proj_w  = (const float*)d_in[6];
  const float* proj_b  = (const float*)d_in[7];
  const float* rpb     = (const float*)d_in[8];
  u16* ws = (u16*)d_ws;

  const unsigned long long BASE = 105906176ULL;   // Wcat + Wproj + xb
  // per-window chunk: (qkvpw 2560 + o1 512) el * 49 * 2B = 301056.
  // em aliases the xb chunk region (dead after main GEMM of that chunk).
  int C = 0;
  for (int cand : {2048, 1024, 512, 256, 128}){
    if (BASE + (unsigned long long)cand * 301056ULL <= ws_size){ C = cand; break; }
  }
  if (C == 0) return;

  u16* Wcat  = ws;
  u16* Wproj = ws + 1310720;
  u16* xb    = ws + 1572864;
  u16* qkvpw = ws + 52953088ULL;
  u16* o1    = qkvpw + (size_t)C * 49 * 2560;

  convk<<<25856, 256, 0, stream>>>(x, qk_w, rev_v_w, wg_w, proj_w, ws);

  bool use256 = ((C * 49) % 256 == 0);
  if (use256){
    hipError_t e = hipFuncSetAttribute((const void*)gemm256p<10>,
        hipFuncAttributeMaxDynamicSharedMemorySize, 131072);
    if (e != hipSuccess) use256 = false;
  }

  const int nch = 2048 / C;
  const int mt128 = C * 49 / 128;
  const int mt256 = C * 49 / 256;
  for (int ch = 0; ch < nch; ch++){
    size_t t0 = (size_t)ch * C * 49;
    u16* em = xb + t0 * 512;            // alias: xb chunk is dead after main GEMM
    if (use256)
      gemm256p<10><<<mt256 * 10, 512, 131072, stream>>>(xb + t0*512, Wcat,
          qk_b, rev_v_b, qkvpw, 2560);
    else
      gemm128<20, 0><<<mt128 * 20, 256, 0, stream>>>(xb + t0*512, 512, Wcat,
          qk_b, rev_v_b, qkvpw, 2560);
    attn_half<<<2 * C, 512, 0, stream>>>(qkvpw, rpb, em);
    hyper2<<<C * 49 / 8, 512, 0, stream>>>(qkvpw, em, o1);
    gemm128<4, 1><<<mt128 * 4, 256, 0, stream>>>(o1, 512, Wproj,
        proj_b, (const float*)nullptr, (float*)d_out + t0*512, 512);
  }
  (void)Wcat; (void)Wproj;
}